// Round 4
// baseline (301.078 us; speedup 1.0000x reference)
//
#include <hip/hip_runtime.h>
#include <stdint.h>

typedef unsigned short u16;
typedef __attribute__((ext_vector_type(8))) short short8;
typedef __attribute__((ext_vector_type(4))) float floatx4;
typedef __attribute__((ext_vector_type(2))) float floatx2;

#define K_DIM 1024
#define N_DIM 1024
#define BM 64
#define BK 32
#define NCHUNK (K_DIM / BK)

__device__ __forceinline__ u16 f2b(float f) {
    union { float f; uint32_t i; } v; v.f = f;
    uint32_t u = v.i;
    return (u16)((u + 0x7FFFu + ((u >> 16) & 1u)) >> 16);   // RNE fp32->bf16
}
__device__ __forceinline__ float b2f(u16 u) {
    union { uint32_t i; float f; } v; v.i = ((uint32_t)u) << 16; return v.f;
}

// ---------- kernel 1: W fp32 -> bf16, packed in MFMA-fragment order ----------
// packed[((tile*32 + kc)*64 + lane)*8 + j] = bf16(W[tile*16 + (lane&15)][kc*32 + (lane>>4)*8 + j])
// tile = wv*4 + ni  (16 waves x 4 col-tiles each)
__global__ __launch_bounds__(256) void pack_w_kernel(const float* __restrict__ w,
                                                     u16* __restrict__ wpk) {
    int gid  = blockIdx.x * 256 + threadIdx.x;   // 0..131071: (tile,kc,lane)
    int lane = gid & 63;
    int kc   = (gid >> 6) & 31;
    int tile = gid >> 11;                        // 0..63
    int n = tile * 16 + (lane & 15);
    int k = kc * 32 + (lane >> 4) * 8;
    const float* src = w + (size_t)n * K_DIM + k;
    floatx4 a = *(const floatx4*)(src);
    floatx4 b = *(const floatx4*)(src + 4);
    short8 o;
    o[0] = (short)f2b(a[0]); o[1] = (short)f2b(a[1]);
    o[2] = (short)f2b(a[2]); o[3] = (short)f2b(a[3]);
    o[4] = (short)f2b(b[0]); o[5] = (short)f2b(b[1]);
    o[6] = (short)f2b(b[2]); o[7] = (short)f2b(b[3]);
    *(short8*)(wpk + (size_t)gid * 8) = o;
}

// ---------- kernel 2: fused GEMM + bias + LayerNorm + (ln+y)*y ----------
// BARRIER-FREE K-loop: no LDS A-staging. Each wave loads its own A fragments
// straight from global fp32 (L1-resident: all 16 waves share the same 8KB/chunk)
// and converts in-loop. Waves free-run (no s_barrier, no cross-wave coupling);
// 4 waves/SIMD provide TLP latency hiding. B via rolling double-buffer from the
// packed-bf16 W (L2-resident). Epilogue identical to the verified round-0 code.
__global__ __launch_bounds__(1024, 4) void fused_gemm_ln_kernel(
    const float* __restrict__ x, const float* __restrict__ y,
    const u16* __restrict__ wpk, const float* __restrict__ bias,
    const float* __restrict__ gamma, const float* __restrict__ beta,
    float* __restrict__ out)
{
    __shared__ __align__(16) u16 zbuf[16 * 1024];     // 32KB bf16 transpose buffer
    __shared__ float ls_sum[64];
    __shared__ float ls_sum2[64];
    __shared__ float ls_mean[64];
    __shared__ float ls_rs[64];

    const int tid  = threadIdx.x;
    const int lane = tid & 63;
    const int wv   = tid >> 6;            // 0..15
    const int q    = lane >> 4;           // quarter-wave id
    const int row0 = blockIdx.x * BM;

    if (tid < 64) { ls_sum[tid] = 0.0f; ls_sum2[tid] = 0.0f; }

    // ---- A: per-lane direct global base. frag(mi,kc) elems:
    //      x[row0 + mi*16 + (lane&15)][kc*32 + (lane>>4)*8 + 0..7]
    const float* ap = x + (size_t)(row0 + (lane & 15)) * K_DIM + ((lane >> 4) << 3);

    // ---- B: packed fragment base; frag (ni,kc) at bp + ni*16384 + kc*512 ----
    const u16* bp = wpk + (size_t)wv * 65536 + lane * 8;

    floatx4 acc[4][4];
#pragma unroll
    for (int mi = 0; mi < 4; ++mi)
#pragma unroll
        for (int ni = 0; ni < 4; ++ni)
            acc[mi][ni] = (floatx4){0.0f, 0.0f, 0.0f, 0.0f};

    // ---- B prologue: chunk 0 ----
    short8 bfr[2][4];
#pragma unroll
    for (int ni = 0; ni < 4; ++ni)
        bfr[0][ni] = *(const short8*)(bp + ni * 16384);

#pragma unroll 2
    for (int kc = 0; kc < NCHUNK; ++kc) {
        const int cur = kc & 1;

        // prefetch next-chunk B (L2) — consumed one full chunk from now
        if (kc + 1 < NCHUNK) {
#pragma unroll
            for (int ni = 0; ni < 4; ++ni)
                bfr[cur ^ 1][ni] = *(const short8*)(bp + ni * 16384 + (kc + 1) * 512);
        }

#pragma unroll
        for (int mi = 0; mi < 4; ++mi) {
            const float* s = ap + (size_t)mi * 16 * K_DIM + kc * BK;
            floatx4 a0 = *(const floatx4*)(s);
            floatx4 a1 = *(const floatx4*)(s + 4);
            short8 af;
            af[0] = (short)f2b(a0[0]); af[1] = (short)f2b(a0[1]);
            af[2] = (short)f2b(a0[2]); af[3] = (short)f2b(a0[3]);
            af[4] = (short)f2b(a1[0]); af[5] = (short)f2b(a1[1]);
            af[6] = (short)f2b(a1[2]); af[7] = (short)f2b(a1[3]);
#pragma unroll
            for (int ni = 0; ni < 4; ++ni)
                acc[mi][ni] = __builtin_amdgcn_mfma_f32_16x16x32_bf16(
                    af, bfr[cur][ni], acc[mi][ni], 0, 0, 0);
        }
    }

    // ---- epilogue: bias (fp32) ----
    float bias_v[4];
#pragma unroll
    for (int ni = 0; ni < 4; ++ni)
        bias_v[ni] = bias[(wv << 6) + (ni << 4) + (lane & 15)];
#pragma unroll
    for (int mi = 0; mi < 4; ++mi)
#pragma unroll
        for (int ni = 0; ni < 4; ++ni)
#pragma unroll
            for (int r = 0; r < 4; ++r)
                acc[mi][ni][r] += bias_v[ni];

    // ls_sum init (top of kernel) must be visible before atomics: first barrier
    __syncthreads();

    // ---- row stats: in-wave 64-col reduce, then LDS float atomics ----
#pragma unroll
    for (int mi = 0; mi < 4; ++mi)
#pragma unroll
        for (int r = 0; r < 4; ++r) {
            float s = 0.0f, s2 = 0.0f;
#pragma unroll
            for (int ni = 0; ni < 4; ++ni) {
                float v = acc[mi][ni][r];
                s += v; s2 += v * v;
            }
#pragma unroll
            for (int m = 1; m < 16; m <<= 1) {
                s  += __shfl_xor(s,  m, 64);
                s2 += __shfl_xor(s2, m, 64);
            }
            if ((lane & 15) == 0) {
                int rl = (mi << 4) + (q << 2) + r;       // C row = q*4 + r
                atomicAdd(&ls_sum[rl], s);
                atomicAdd(&ls_sum2[rl], s2);
            }
        }

    __syncthreads();
    if (tid < 64) {
        float mean = ls_sum[tid] * (1.0f / 1024.0f);
        float var  = ls_sum2[tid] * (1.0f / 1024.0f) - mean * mean;
        ls_mean[tid] = mean;
        ls_rs[tid]   = rsqrtf(var + 1e-5f);
    }

    // ---- per 16-row slice: LDS transpose (bf16), coalesced fp32 LN+res+mul ----
    for (int mi = 0; mi < 4; ++mi) {
#pragma unroll
        for (int ni = 0; ni < 4; ++ni)
#pragma unroll
            for (int r = 0; r < 4; ++r) {
                int lr   = (q << 2) + r;                          // local row 0..15
                int lin  = (((wv << 6) + (ni << 4) + (lane & 15)) << 1);
                int phys = lr * 2048 + (lin ^ (q << 5));          // swizzled
                *(u16*)((char*)zbuf + phys) = f2b(acc[mi][ni][r]);
            }
        __syncthreads();
#pragma unroll
        for (int it = 0; it < 2; ++it) {
            int row  = (tid >> 7) + (it << 3);                    // 0..15
            int c8   = tid & 127;                                 // 16B chunk id
            int phys = row * 2048 + ((c8 << 4) ^ (((row >> 2) & 3) << 5));
            short8 z8 = *(const short8*)((const char*)zbuf + phys);
            int grow  = row0 + (mi << 4) + row;
            float mean = ls_mean[(mi << 4) + row];
            float rs   = ls_rs[(mi << 4) + row];
            const float* yp = y     + (size_t)grow * N_DIM + c8 * 8;
            const float* gp = gamma + c8 * 8;
            const float* bpv = beta + c8 * 8;
            float*       op = out   + (size_t)grow * N_DIM + c8 * 8;
            floatx4 y0 = *(const floatx4*)(yp);
            floatx4 y1 = *(const floatx4*)(yp + 4);
            floatx4 g0 = *(const floatx4*)(gp);
            floatx4 g1 = *(const floatx4*)(gp + 4);
            floatx4 b0 = *(const floatx4*)(bpv);
            floatx4 b1 = *(const floatx4*)(bpv + 4);
            floatx4 o0, o1;
#pragma unroll
            for (int e = 0; e < 4; ++e) {
                float zv = b2f((u16)z8[e]);
                o0[e] = ((zv - mean) * rs * g0[e] + b0[e] + y0[e]) * y0[e];
            }
#pragma unroll
            for (int e = 0; e < 4; ++e) {
                float zv = b2f((u16)z8[e + 4]);
                o1[e] = ((zv - mean) * rs * g1[e] + b1[e] + y1[e]) * y1[e];
            }
            *(floatx4*)(op)     = o0;
            *(floatx4*)(op + 4) = o1;
        }
        __syncthreads();
    }
}

extern "C" void kernel_launch(void* const* d_in, const int* in_sizes, int n_in,
                              void* d_out, int out_size, void* d_ws, size_t ws_size,
                              hipStream_t stream) {
    const float* x     = (const float*)d_in[0];
    const float* y     = (const float*)d_in[1];
    const float* wgt   = (const float*)d_in[2];
    const float* bias  = (const float*)d_in[3];
    const float* gamma = (const float*)d_in[4];
    const float* beta  = (const float*)d_in[5];
    float* out = (float*)d_out;
    u16* wpk = (u16*)d_ws;                               // 2MB packed bf16 W

    pack_w_kernel<<<512, 256, 0, stream>>>(wgt, wpk);

    const int M = in_sizes[0] / K_DIM;                   // 16384
    fused_gemm_ln_kernel<<<M / BM, 1024, 0, stream>>>(x, y, wpk, bias, gamma, beta, out);
}

// Round 5
// 217.879 us; speedup vs baseline: 1.3819x; 1.3819x over previous
//
#include <hip/hip_runtime.h>
#include <stdint.h>

typedef unsigned short u16;
typedef __attribute__((ext_vector_type(8))) short short8;
typedef __attribute__((ext_vector_type(4))) float floatx4;
typedef __attribute__((ext_vector_type(2))) float floatx2;

#define K_DIM 1024
#define N_DIM 1024
#define BM 64
#define BK 32
#define NCHUNK (K_DIM / BK)

__device__ __forceinline__ u16 f2b(float f) {
    union { float f; uint32_t i; } v; v.f = f;
    uint32_t u = v.i;
    return (u16)((u + 0x7FFFu + ((u >> 16) & 1u)) >> 16);   // RNE fp32->bf16
}
__device__ __forceinline__ float b2f(u16 u) {
    union { uint32_t i; float f; } v; v.i = ((uint32_t)u) << 16; return v.f;
}

// ---------- kernel 1: W fp32 -> bf16, packed in MFMA-fragment order ----------
// packed[((tile*32 + kc)*64 + lane)*8 + j] = bf16(W[tile*16 + (lane&15)][kc*32 + (lane>>4)*8 + j])
__global__ __launch_bounds__(256) void pack_w_kernel(const float* __restrict__ w,
                                                     u16* __restrict__ wpk) {
    int gid  = blockIdx.x * 256 + threadIdx.x;   // 0..131071: (tile,kc,lane)
    int lane = gid & 63;
    int kc   = (gid >> 6) & 31;
    int tile = gid >> 11;                        // 0..63
    int n = tile * 16 + (lane & 15);
    int k = kc * 32 + (lane >> 4) * 8;
    const float* src = w + (size_t)n * K_DIM + k;
    floatx4 a = *(const floatx4*)(src);
    floatx4 b = *(const floatx4*)(src + 4);
    short8 o;
    o[0] = (short)f2b(a[0]); o[1] = (short)f2b(a[1]);
    o[2] = (short)f2b(a[2]); o[3] = (short)f2b(a[3]);
    o[4] = (short)f2b(b[0]); o[5] = (short)f2b(b[1]);
    o[6] = (short)f2b(b[2]); o[7] = (short)f2b(b[3]);
    *(short8*)(wpk + (size_t)gid * 8) = o;
}

// ---------- kernel 2: fused GEMM + bias + LayerNorm + (ln+y)*y ----------
// R2 geometry/layouts (verified), K-loop restructured into the 8-phase-style
// schedule (T3+T4+T5): per chunk, TWO sub-phases, each
//   { 2x ds_read A ; issue half of next-chunk B ; (far-A load | A-stage write) }
//   -> s_barrier -> lgkmcnt(0) -> setprio(1) 8x MFMA setprio(0) -> s_barrier
// Global prefetches are NEVER drained in-loop (no vmcnt(0)); the compiler
// places counted vmcnt waits at first use (~1 chunk for B, ~2.5 chunks for A).
__global__ __launch_bounds__(1024) void fused_gemm_ln_kernel(
    const float* __restrict__ x, const float* __restrict__ y,
    const u16* __restrict__ wpk, const float* __restrict__ bias,
    const float* __restrict__ gamma, const float* __restrict__ beta,
    float* __restrict__ out)
{
    __shared__ __align__(16) u16 lds_a[2][BM * BK];   // 2 x 4KB bf16 A tiles, swizzled
    __shared__ __align__(16) u16 zbuf[16 * 1024];     // 32KB bf16 transpose buffer
    __shared__ float ls_sum[64];
    __shared__ float ls_sum2[64];
    __shared__ float ls_mean[64];
    __shared__ float ls_rs[64];

    const int tid  = threadIdx.x;
    const int lane = tid & 63;
    const int wv   = tid >> 6;            // 0..15
    const int q    = lane >> 4;           // quarter-wave id
    const int row0 = blockIdx.x * BM;

    if (tid < 64) { ls_sum[tid] = 0.0f; ls_sum2[tid] = 0.0f; }

    // ---- A staging (all 1024 threads, 2 fp32 each per chunk) ----
    const int sr = tid >> 4;              // 0..63
    const int sk = (tid & 15) << 1;       // even 0..30
    const float* s_src = x + (size_t)(row0 + sr) * K_DIM + sk;
    const int s_qs  = (sk >> 3) ^ ((sr >> 1) & 3);
    const int s_off = sr * 64 + s_qs * 16 + (sk & 7) * 2;

    // ---- B: packed fragment base; frag (ni,kc) at bp + ni*16384 + kc*512 ----
    const u16* bp = wpk + (size_t)wv * 65536 + lane * 8;

    // ---- A fragment LDS base offset (mi-invariant swizzle) ----
    const int a_base = (lane & 15) * 64 + (q ^ (((lane & 15) >> 1) & 3)) * 16;

    floatx4 acc[4][4];
#pragma unroll
    for (int mi = 0; mi < 4; ++mi)
#pragma unroll
        for (int ni = 0; ni < 4; ++ni)
            acc[mi][ni] = (floatx4){0.0f, 0.0f, 0.0f, 0.0f};

    // ---- prologue: stage A chunk0; prefetch A chunks 1,2; B chunk0 ----
    {
        floatx2 v0 = *(const floatx2*)(s_src);
        uint32_t p = (uint32_t)f2b(v0[0]) | ((uint32_t)f2b(v0[1]) << 16);
        *(uint32_t*)((char*)(&lds_a[0][0]) + s_off) = p;
    }
    floatx2 va_next = *(const floatx2*)(s_src + BK);        // chunk 1 (in flight)
    floatx2 va_far  = *(const floatx2*)(s_src + 2 * BK);    // chunk 2 (in flight)

    short8 bfr[2][4];
#pragma unroll
    for (int ni = 0; ni < 4; ++ni)
        bfr[0][ni] = *(const short8*)(bp + ni * 16384);     // kc=0

    __syncthreads();   // chunk-0 A staging visible

#pragma unroll 2
    for (int kc = 0; kc < NCHUNK; ++kc) {
        const int cur = kc & 1;
        const int nxt = cur ^ 1;
        const char* ab = (const char*)(&lds_a[cur][0]);
        const int kn = (kc + 1 < NCHUNK) ? (kc + 1) : kc;    // next B chunk (clamped)

        // ================= phase 0 =================
        short8 af0 = *(const short8*)(ab + a_base);
        short8 af1 = *(const short8*)(ab + a_base + 1024);
        // issue half of next-chunk B (ni 0,1) into the other parity buffer
        bfr[nxt][0] = *(const short8*)(bp + 0 * 16384 + kn * 512);
        bfr[nxt][1] = *(const short8*)(bp + 1 * 16384 + kn * 512);
        // far A global load (chunk kc+3, clamped) — lands ~2.5 chunks from now
        const int ka = (kc + 3 < NCHUNK) ? (kc + 3) : (NCHUNK - 1);
        floatx2 vnew = *(const floatx2*)(s_src + ka * BK);

        __builtin_amdgcn_s_barrier();
        asm volatile("s_waitcnt lgkmcnt(0)" ::: "memory");
        __builtin_amdgcn_s_setprio(1);
#pragma unroll
        for (int ni = 0; ni < 4; ++ni) {
            acc[0][ni] = __builtin_amdgcn_mfma_f32_16x16x32_bf16(
                af0, bfr[cur][ni], acc[0][ni], 0, 0, 0);
            acc[1][ni] = __builtin_amdgcn_mfma_f32_16x16x32_bf16(
                af1, bfr[cur][ni], acc[1][ni], 0, 0, 0);
        }
        __builtin_amdgcn_s_setprio(0);
        __builtin_amdgcn_s_barrier();

        // ================= phase 1 =================
        short8 af2 = *(const short8*)(ab + a_base + 2048);
        short8 af3 = *(const short8*)(ab + a_base + 3072);
        // other half of next-chunk B (ni 2,3)
        bfr[nxt][2] = *(const short8*)(bp + 2 * 16384 + kn * 512);
        bfr[nxt][3] = *(const short8*)(bp + 3 * 16384 + kn * 512);
        // stage chunk kc+1 A from registers (loaded ~2.5 chunks ago), rotate
        {
            uint32_t p = (uint32_t)f2b(va_next[0]) | ((uint32_t)f2b(va_next[1]) << 16);
            *(uint32_t*)((char*)(&lds_a[nxt][0]) + s_off) = p;
            va_next = va_far;
            va_far  = vnew;
        }

        __builtin_amdgcn_s_barrier();
        asm volatile("s_waitcnt lgkmcnt(0)" ::: "memory");   // drains own ds_write too
        __builtin_amdgcn_s_setprio(1);
#pragma unroll
        for (int ni = 0; ni < 4; ++ni) {
            acc[2][ni] = __builtin_amdgcn_mfma_f32_16x16x32_bf16(
                af2, bfr[cur][ni], acc[2][ni], 0, 0, 0);
            acc[3][ni] = __builtin_amdgcn_mfma_f32_16x16x32_bf16(
                af3, bfr[cur][ni], acc[3][ni], 0, 0, 0);
        }
        __builtin_amdgcn_s_setprio(0);
        __builtin_amdgcn_s_barrier();
        // all waves' ds_writes drained before this barrier -> next chunk reads safe
    }

    // ---- epilogue: bias (fp32) ----
    float bias_v[4];
#pragma unroll
    for (int ni = 0; ni < 4; ++ni)
        bias_v[ni] = bias[(wv << 6) + (ni << 4) + (lane & 15)];
#pragma unroll
    for (int mi = 0; mi < 4; ++mi)
#pragma unroll
        for (int ni = 0; ni < 4; ++ni)
#pragma unroll
            for (int r = 0; r < 4; ++r)
                acc[mi][ni][r] += bias_v[ni];

    // ---- row stats: in-wave 64-col reduce, then LDS float atomics ----
#pragma unroll
    for (int mi = 0; mi < 4; ++mi)
#pragma unroll
        for (int r = 0; r < 4; ++r) {
            float s = 0.0f, s2 = 0.0f;
#pragma unroll
            for (int ni = 0; ni < 4; ++ni) {
                float v = acc[mi][ni][r];
                s += v; s2 += v * v;
            }
#pragma unroll
            for (int m = 1; m < 16; m <<= 1) {
                s  += __shfl_xor(s,  m, 64);
                s2 += __shfl_xor(s2, m, 64);
            }
            if ((lane & 15) == 0) {
                int rl = (mi << 4) + (q << 2) + r;       // C row = q*4 + r
                atomicAdd(&ls_sum[rl], s);
                atomicAdd(&ls_sum2[rl], s2);
            }
        }

    __syncthreads();
    if (tid < 64) {
        float mean = ls_sum[tid] * (1.0f / 1024.0f);
        float var  = ls_sum2[tid] * (1.0f / 1024.0f) - mean * mean;
        ls_mean[tid] = mean;
        ls_rs[tid]   = rsqrtf(var + 1e-5f);
    }

    // ---- per 16-row slice: LDS transpose (bf16), coalesced fp32 LN+res+mul ----
    for (int mi = 0; mi < 4; ++mi) {
#pragma unroll
        for (int ni = 0; ni < 4; ++ni)
#pragma unroll
            for (int r = 0; r < 4; ++r) {
                int lr   = (q << 2) + r;                          // local row 0..15
                int lin  = (((wv << 6) + (ni << 4) + (lane & 15)) << 1);
                int phys = lr * 2048 + (lin ^ (q << 5));          // swizzled
                *(u16*)((char*)zbuf + phys) = f2b(acc[mi][ni][r]);
            }
        __syncthreads();
#pragma unroll
        for (int it = 0; it < 2; ++it) {
            int row  = (tid >> 7) + (it << 3);                    // 0..15
            int c8   = tid & 127;                                 // 16B chunk id
            int phys = row * 2048 + ((c8 << 4) ^ (((row >> 2) & 3) << 5));
            short8 z8 = *(const short8*)((const char*)zbuf + phys);
            int grow  = row0 + (mi << 4) + row;
            float mean = ls_mean[(mi << 4) + row];
            float rs   = ls_rs[(mi << 4) + row];
            const float* yp = y     + (size_t)grow * N_DIM + c8 * 8;
            const float* gp = gamma + c8 * 8;
            const float* bpv = beta + c8 * 8;
            float*       op = out   + (size_t)grow * N_DIM + c8 * 8;
            floatx4 y0 = *(const floatx4*)(yp);
            floatx4 y1 = *(const floatx4*)(yp + 4);
            floatx4 g0 = *(const floatx4*)(gp);
            floatx4 g1 = *(const floatx4*)(gp + 4);
            floatx4 b0 = *(const floatx4*)(bpv);
            floatx4 b1 = *(const floatx4*)(bpv + 4);
            floatx4 o0, o1;
#pragma unroll
            for (int e = 0; e < 4; ++e) {
                float zv = b2f((u16)z8[e]);
                o0[e] = ((zv - mean) * rs * g0[e] + b0[e] + y0[e]) * y0[e];
            }
#pragma unroll
            for (int e = 0; e < 4; ++e) {
                float zv = b2f((u16)z8[e + 4]);
                o1[e] = ((zv - mean) * rs * g1[e] + b1[e] + y1[e]) * y1[e];
            }
            *(floatx4*)(op)     = o0;
            *(floatx4*)(op + 4) = o1;
        }
        __syncthreads();
    }
}

extern "C" void kernel_launch(void* const* d_in, const int* in_sizes, int n_in,
                              void* d_out, int out_size, void* d_ws, size_t ws_size,
                              hipStream_t stream) {
    const float* x     = (const float*)d_in[0];
    const float* y     = (const float*)d_in[1];
    const float* wgt   = (const float*)d_in[2];
    const float* bias  = (const float*)d_in[3];
    const float* gamma = (const float*)d_in[4];
    const float* beta  = (const float*)d_in[5];
    float* out = (float*)d_out;
    u16* wpk = (u16*)d_ws;                               // 2MB packed bf16 W

    pack_w_kernel<<<512, 256, 0, stream>>>(wgt, wpk);

    const int M = in_sizes[0] / K_DIM;                   // 16384
    fused_gemm_ln_kernel<<<M / BM, 1024, 0, stream>>>(x, y, wpk, bias, gamma, beta, out);
}

// Round 6
// 216.900 us; speedup vs baseline: 1.3881x; 1.0045x over previous
//
#include <hip/hip_runtime.h>
#include <stdint.h>

typedef unsigned short u16;
typedef __attribute__((ext_vector_type(8))) short short8;
typedef __attribute__((ext_vector_type(4))) float floatx4;
typedef __attribute__((ext_vector_type(2))) float floatx2;

#define K_DIM 1024
#define N_DIM 1024
#define BM 64
#define BK 32
#define NCHUNK (K_DIM / BK)
#define HCHUNK (NCHUNK / 2)

__device__ __forceinline__ u16 f2b(float f) {
    union { float f; uint32_t i; } v; v.f = f;
    uint32_t u = v.i;
    return (u16)((u + 0x7FFFu + ((u >> 16) & 1u)) >> 16);   // RNE fp32->bf16
}
__device__ __forceinline__ float b2f(u16 u) {
    union { uint32_t i; float f; } v; v.i = ((uint32_t)u) << 16; return v.f;
}

// ---------- kernel 1: W fp32 -> bf16, packed in MFMA-fragment order ----------
// packed[((tile*32 + kc)*64 + lane)*8 + j] = bf16(W[tile*16 + (lane&15)][kc*32 + (lane>>4)*8 + j])
__global__ __launch_bounds__(256) void pack_w_kernel(const float* __restrict__ w,
                                                     u16* __restrict__ wpk) {
    int gid  = blockIdx.x * 256 + threadIdx.x;   // 0..131071: (tile,kc,lane)
    int lane = gid & 63;
    int kc   = (gid >> 6) & 31;
    int tile = gid >> 11;                        // 0..63
    int n = tile * 16 + (lane & 15);
    int k = kc * 32 + (lane >> 4) * 8;
    const float* src = w + (size_t)n * K_DIM + k;
    floatx4 a = *(const floatx4*)(src);
    floatx4 b = *(const floatx4*)(src + 4);
    short8 o;
    o[0] = (short)f2b(a[0]); o[1] = (short)f2b(a[1]);
    o[2] = (short)f2b(a[2]); o[3] = (short)f2b(a[3]);
    o[4] = (short)f2b(b[0]); o[5] = (short)f2b(b[1]);
    o[6] = (short)f2b(b[2]); o[7] = (short)f2b(b[3]);
    *(short8*)(wpk + (size_t)gid * 8) = o;
}

// ---------- kernel 2: fused GEMM + bias + LayerNorm + (ln+y)*y ----------
// HALF-K BULK A-STAGING: the A tile for 16 chunks (64 rows x 512 k bf16 = 64KB)
// is staged into LDS ONCE (verified per-chunk swizzle layout, replicated as
// 16 x 4KB slabs). The K-loop is then BARRIER-FREE and ds_write-free: per chunk
// just {4 conflict-free ds_read_b128 + 16 MFMA + 4 parity B prefetch loads}.
// Waves free-run at 4/SIMD. Only 3 barrier points total (prologue stage,
// half-K restage x2) vs 128 barrier crossings in the per-chunk-staged variants.
__global__ __launch_bounds__(1024) void fused_gemm_ln_kernel(
    const float* __restrict__ x, const float* __restrict__ y,
    const u16* __restrict__ wpk, const float* __restrict__ bias,
    const float* __restrict__ gamma, const float* __restrict__ beta,
    float* __restrict__ out)
{
    __shared__ __align__(16) u16 lds16[HCHUNK * BM * BK]; // 16 x 4KB A slabs (64KB)
    __shared__ __align__(16) u16 zbuf[16 * 1024];         // 32KB bf16 transpose buffer
    __shared__ float ls_sum[64];
    __shared__ float ls_sum2[64];
    __shared__ float ls_mean[64];
    __shared__ float ls_rs[64];

    const int tid  = threadIdx.x;
    const int lane = tid & 63;
    const int wv   = tid >> 6;            // 0..15
    const int q    = lane >> 4;           // quarter-wave id
    const int row0 = blockIdx.x * BM;

    if (tid < 64) { ls_sum[tid] = 0.0f; ls_sum2[tid] = 0.0f; }

    // ---- A staging addressing (verified): 2 fp32 per thread per chunk ----
    const int sr = tid >> 4;              // 0..63
    const int sk = (tid & 15) << 1;       // even 0..30
    const float* s_src = x + (size_t)(row0 + sr) * K_DIM + sk;
    const int s_qs  = (sk >> 3) ^ ((sr >> 1) & 3);
    const int s_off = sr * 64 + s_qs * 16 + (sk & 7) * 2;   // byte offset in 4KB slab

    // ---- B: packed fragment base; frag (ni,kc) at bp + ni*16384 + kc*512 ----
    const u16* bp = wpk + (size_t)wv * 65536 + lane * 8;

    // ---- A fragment LDS base offset within a slab (verified swizzle) ----
    const int a_base = (lane & 15) * 64 + (q ^ (((lane & 15) >> 1) & 3)) * 16;

    floatx4 acc[4][4];
#pragma unroll
    for (int mi = 0; mi < 4; ++mi)
#pragma unroll
        for (int ni = 0; ni < 4; ++ni)
            acc[mi][ni] = (floatx4){0.0f, 0.0f, 0.0f, 0.0f};

    // ---- prologue: bulk-stage A half 0 (chunks 0..15), prefetch B chunk 0 ----
#pragma unroll 4
    for (int c = 0; c < HCHUNK; ++c) {
        floatx2 v = *(const floatx2*)(s_src + c * BK);
        uint32_t p = (uint32_t)f2b(v[0]) | ((uint32_t)f2b(v[1]) << 16);
        *(uint32_t*)((char*)lds16 + c * 4096 + s_off) = p;
    }

    short8 bfr[2][4];
#pragma unroll
    for (int ni = 0; ni < 4; ++ni)
        bfr[0][ni] = *(const short8*)(bp + ni * 16384);     // kc=0

    __syncthreads();   // half-0 A staging visible; also covers ls_sum init

    for (int half = 0; half < 2; ++half) {
        if (half == 1) {
            __syncthreads();   // all waves done reading half-0 slabs
#pragma unroll 4
            for (int c = 0; c < HCHUNK; ++c) {
                floatx2 v = *(const floatx2*)(s_src + (HCHUNK + c) * BK);
                uint32_t p = (uint32_t)f2b(v[0]) | ((uint32_t)f2b(v[1]) << 16);
                *(uint32_t*)((char*)lds16 + c * 4096 + s_off) = p;
            }
            __syncthreads();   // half-1 staging visible
        }

#pragma unroll 2
        for (int c = 0; c < HCHUNK; ++c) {
            const int kc  = half * HCHUNK + c;
            const int cur = kc & 1;            // == c&1 (HCHUNK even): static
            const int nxt = cur ^ 1;
            const char* ab = (const char*)lds16 + c * 4096;

            // A frags for this chunk (read-only LDS, conflict-free)
            short8 af0 = *(const short8*)(ab + a_base);
            short8 af1 = *(const short8*)(ab + a_base + 1024);
            short8 af2 = *(const short8*)(ab + a_base + 2048);
            short8 af3 = *(const short8*)(ab + a_base + 3072);

            // parity B prefetch for chunk kc+1 (clamped at the end)
            const int kn = (kc + 1 < NCHUNK) ? (kc + 1) : kc;
#pragma unroll
            for (int ni = 0; ni < 4; ++ni)
                bfr[nxt][ni] = *(const short8*)(bp + ni * 16384 + kn * 512);

#pragma unroll
            for (int ni = 0; ni < 4; ++ni) {
                acc[0][ni] = __builtin_amdgcn_mfma_f32_16x16x32_bf16(
                    af0, bfr[cur][ni], acc[0][ni], 0, 0, 0);
                acc[1][ni] = __builtin_amdgcn_mfma_f32_16x16x32_bf16(
                    af1, bfr[cur][ni], acc[1][ni], 0, 0, 0);
                acc[2][ni] = __builtin_amdgcn_mfma_f32_16x16x32_bf16(
                    af2, bfr[cur][ni], acc[2][ni], 0, 0, 0);
                acc[3][ni] = __builtin_amdgcn_mfma_f32_16x16x32_bf16(
                    af3, bfr[cur][ni], acc[3][ni], 0, 0, 0);
            }
        }
    }

    // ---- epilogue: bias (fp32) ----
    float bias_v[4];
#pragma unroll
    for (int ni = 0; ni < 4; ++ni)
        bias_v[ni] = bias[(wv << 6) + (ni << 4) + (lane & 15)];
#pragma unroll
    for (int mi = 0; mi < 4; ++mi)
#pragma unroll
        for (int ni = 0; ni < 4; ++ni)
#pragma unroll
            for (int r = 0; r < 4; ++r)
                acc[mi][ni][r] += bias_v[ni];

    __syncthreads();   // all waves past K-loop before stats atomics

    // ---- row stats: in-wave 64-col reduce, then LDS float atomics ----
#pragma unroll
    for (int mi = 0; mi < 4; ++mi)
#pragma unroll
        for (int r = 0; r < 4; ++r) {
            float s = 0.0f, s2 = 0.0f;
#pragma unroll
            for (int ni = 0; ni < 4; ++ni) {
                float v = acc[mi][ni][r];
                s += v; s2 += v * v;
            }
#pragma unroll
            for (int m = 1; m < 16; m <<= 1) {
                s  += __shfl_xor(s,  m, 64);
                s2 += __shfl_xor(s2, m, 64);
            }
            if ((lane & 15) == 0) {
                int rl = (mi << 4) + (q << 2) + r;       // C row = q*4 + r
                atomicAdd(&ls_sum[rl], s);
                atomicAdd(&ls_sum2[rl], s2);
            }
        }

    __syncthreads();
    if (tid < 64) {
        float mean = ls_sum[tid] * (1.0f / 1024.0f);
        float var  = ls_sum2[tid] * (1.0f / 1024.0f) - mean * mean;
        ls_mean[tid] = mean;
        ls_rs[tid]   = rsqrtf(var + 1e-5f);
    }

    // ---- per 16-row slice: LDS transpose (bf16), coalesced fp32 LN+res+mul ----
    for (int mi = 0; mi < 4; ++mi) {
#pragma unroll
        for (int ni = 0; ni < 4; ++ni)
#pragma unroll
            for (int r = 0; r < 4; ++r) {
                int lr   = (q << 2) + r;                          // local row 0..15
                int lin  = (((wv << 6) + (ni << 4) + (lane & 15)) << 1);
                int phys = lr * 2048 + (lin ^ (q << 5));          // swizzled
                *(u16*)((char*)zbuf + phys) = f2b(acc[mi][ni][r]);
            }
        __syncthreads();
#pragma unroll
        for (int it = 0; it < 2; ++it) {
            int row  = (tid >> 7) + (it << 3);                    // 0..15
            int c8   = tid & 127;                                 // 16B chunk id
            int phys = row * 2048 + ((c8 << 4) ^ (((row >> 2) & 3) << 5));
            short8 z8 = *(const short8*)((const char*)zbuf + phys);
            int grow  = row0 + (mi << 4) + row;
            float mean = ls_mean[(mi << 4) + row];
            float rs   = ls_rs[(mi << 4) + row];
            const float* yp = y     + (size_t)grow * N_DIM + c8 * 8;
            const float* gp = gamma + c8 * 8;
            const float* bpv = beta + c8 * 8;
            float*       op = out   + (size_t)grow * N_DIM + c8 * 8;
            floatx4 y0 = *(const floatx4*)(yp);
            floatx4 y1 = *(const floatx4*)(yp + 4);
            floatx4 g0 = *(const floatx4*)(gp);
            floatx4 g1 = *(const floatx4*)(gp + 4);
            floatx4 b0 = *(const floatx4*)(bpv);
            floatx4 b1 = *(const floatx4*)(bpv + 4);
            floatx4 o0, o1;
#pragma unroll
            for (int e = 0; e < 4; ++e) {
                float zv = b2f((u16)z8[e]);
                o0[e] = ((zv - mean) * rs * g0[e] + b0[e] + y0[e]) * y0[e];
            }
#pragma unroll
            for (int e = 0; e < 4; ++e) {
                float zv = b2f((u16)z8[e + 4]);
                o1[e] = ((zv - mean) * rs * g1[e] + b1[e] + y1[e]) * y1[e];
            }
            *(floatx4*)(op)     = o0;
            *(floatx4*)(op + 4) = o1;
        }
        __syncthreads();
    }
}

extern "C" void kernel_launch(void* const* d_in, const int* in_sizes, int n_in,
                              void* d_out, int out_size, void* d_ws, size_t ws_size,
                              hipStream_t stream) {
    const float* x     = (const float*)d_in[0];
    const float* y     = (const float*)d_in[1];
    const float* wgt   = (const float*)d_in[2];
    const float* bias  = (const float*)d_in[3];
    const float* gamma = (const float*)d_in[4];
    const float* beta  = (const float*)d_in[5];
    float* out = (float*)d_out;
    u16* wpk = (u16*)d_ws;                               // 2MB packed bf16 W

    pack_w_kernel<<<512, 256, 0, stream>>>(wgt, wpk);

    const int M = in_sizes[0] / K_DIM;                   // 16384
    fused_gemm_ln_kernel<<<M / BM, 1024, 0, stream>>>(x, y, wpk, bias, gamma, beta, out);
}